// Round 1
// 87.134 us; speedup vs baseline: 1.0189x; 1.0189x over previous
//
#include <hip/hip_runtime.h>

#define BB 4
#define NN 8192

typedef _Float16 f16;
typedef _Float16 f16x8 __attribute__((ext_vector_type(8)));
typedef float f32x16 __attribute__((ext_vector_type(16)));

// ws layout: APR, BGT packed f16 (1 MB each) | prow 1 MB | pcol 4 MB | res
#define SZ_PACK (BB * NN * 16)                      // f16 elements per packed array
#define OFF_PROW_BYTES (2 * SZ_PACK * 2)            // 2 MB
#define SZ_PROW (BB * 8 * NN)                       // floats: [b][eighth][row]
#define OFF_PCOL_BYTES (OFF_PROW_BYTES + SZ_PROW * 4)
#define SZ_PCOL (BB * 32 * NN)                      // floats: [b][wgrow][col]
#define OFF_RES_BYTES (OFF_PCOL_BYTES + SZ_PCOL * 4)

// ---------------- K1: build packed K-slot records (single matrix now) ------
// A-role pr: [-2ph(3), -2ph(3), -2pl(3), p2h, p2l, 1, 1, 0,0,0]
// B-role gt: [ gh(3),   gl(3),   gh(3),  1, 1, g2h|32768, g2l|0, 0,0,0]
// d^2 = -2 p.g (exact-split) + |p|^2 + |g|^2; invalid gt col -> ~+32768.
__global__ __launch_bounds__(256) void k_init(
    const float* __restrict__ pr, const float* __restrict__ gt,
    const int* __restrict__ valid,
    f16* __restrict__ APR, f16* __restrict__ BGT, float* __restrict__ res) {
  int i = blockIdx.x * 256 + threadIdx.x;
  if (blockIdx.x == 0 && threadIdx.x < 16) res[threadIdx.x] = 0.0f;
  if (i >= BB * NN) return;
  float px = pr[3 * i], py = pr[3 * i + 1], pz = pr[3 * i + 2];
  float gx = gt[3 * i], gy = gt[3 * i + 1], gz = gt[3 * i + 2];
  int vld = valid[i] != 0;

  f16 phx = (f16)px, phy = (f16)py, phz = (f16)pz;
  f16 plx = (f16)(px - (float)phx), ply = (f16)(py - (float)phy), plz = (f16)(pz - (float)phz);
  float p2 = px * px + py * py + pz * pz;
  f16 p2h = (f16)p2, p2l = (f16)(p2 - (float)p2h);

  f16 ghx = (f16)gx, ghy = (f16)gy, ghz = (f16)gz;
  f16 glx = (f16)(gx - (float)ghx), gly = (f16)(gy - (float)ghy), glz = (f16)(gz - (float)ghz);
  float g2 = gx * gx + gy * gy + gz * gz;
  f16 g2h = (f16)g2, g2l = (f16)(g2 - (float)g2h);
  f16 g2hm = vld ? g2h : (f16)32768.0f;
  f16 g2lm = vld ? g2l : (f16)0.0f;

  const f16 one = (f16)1.0f, zero = (f16)0.0f;
  union Rec { f16 h[16]; uint4 u[2]; };

  Rec ra;  // APR
  ra.h[0] = (f16)(-2.f * (float)phx); ra.h[1] = (f16)(-2.f * (float)phy); ra.h[2] = (f16)(-2.f * (float)phz);
  ra.h[3] = ra.h[0]; ra.h[4] = ra.h[1]; ra.h[5] = ra.h[2];
  ra.h[6] = (f16)(-2.f * (float)plx); ra.h[7] = (f16)(-2.f * (float)ply); ra.h[8] = (f16)(-2.f * (float)plz);
  ra.h[9] = p2h; ra.h[10] = p2l; ra.h[11] = one; ra.h[12] = one;
  ra.h[13] = zero; ra.h[14] = zero; ra.h[15] = zero;
  ((uint4*)APR)[2 * i] = ra.u[0]; ((uint4*)APR)[2 * i + 1] = ra.u[1];

  Rec rd;  // BGT (masked)
  rd.h[0] = ghx; rd.h[1] = ghy; rd.h[2] = ghz;
  rd.h[3] = glx; rd.h[4] = gly; rd.h[5] = glz;
  rd.h[6] = ghx; rd.h[7] = ghy; rd.h[8] = ghz;
  rd.h[9] = one; rd.h[10] = one; rd.h[11] = g2hm; rd.h[12] = g2lm;
  rd.h[13] = zero; rd.h[14] = zero; rd.h[15] = zero;
  ((uint4*)BGT)[2 * i] = rd.u[0]; ((uint4*)BGT)[2 * i + 1] = rd.u[1];
}

// ---------------- K2: single MFMA pass, row-min AND col-min ----------------
// grid 1024: b(2) | eighth(3) | wgrow(5). wg = 4 waves x 64 rows = 256 rows,
// cols = eighth*1024 .. +1024 in 2 chunks of 512. LDS 24 KB -> 4 wg/CU (grid cap).
// Each wave holds TWO A fragments (rows +0, +32) so every B ds_read feeds 2 MFMAs.
__device__ __forceinline__ float min16(const f32x16& d) {
  float v = fminf(fminf(d[0], d[1]), d[2]);
  v = fminf(fminf(v, d[3]), d[4]);
  v = fminf(fminf(v, d[5]), d[6]);
  v = fminf(fminf(v, d[7]), d[8]);
  v = fminf(fminf(v, d[9]), d[10]);
  v = fminf(fminf(v, d[11]), d[12]);
  v = fminf(fminf(v, d[13]), d[14]);
  return fminf(v, d[15]);
}

__global__ __launch_bounds__(256, 4) void k_dist(
    const f16* __restrict__ APR, const f16* __restrict__ BGT,
    float* __restrict__ prow, float* __restrict__ pcol) {
  __shared__ f16 ldsB[2 * 512 * 8];      // 16 KB: [half-record r][pt j][8]
  __shared__ float colmin_s[4][512];     // 8 KB: per-wave col-min of chunk
  int id = blockIdx.x;
  int wgrow  = id & 31;
  int eighth = (id >> 5) & 7;
  int b      = id >> 8;
  int tid = threadIdx.x;
  int wave = tid >> 6, lane = tid & 63;
  int nn = lane & 31, q = lane >> 5;

  // A fragments: A[m=lane&31][k=(lane>>5)*8 + j]
  const f16* Ab = APR + ((size_t)b * NN + wgrow * 256 + wave * 64 + nn) * 16 + q * 8;
  f16x8 af0 = *(const f16x8*)Ab;
  f16x8 af1 = *(const f16x8*)(Ab + 32 * 16);

  f32x16 zc = {};
  f32x16 m0, m1;
#pragma unroll
  for (int i = 0; i < 16; ++i) { m0[i] = 1e38f; m1[i] = 1e38f; }

  const uint4* gsrc = (const uint4*)(BGT + ((size_t)b * NN + eighth * 1024) * 16);
  uint4* ldsu = (uint4*)ldsB;
  const f16x8* lf = (const f16x8*)ldsB;

  for (int chunk = 0; chunk < 2; ++chunk) {
    const uint4* src = gsrc + chunk * 1024;
#pragma unroll
    for (int k = 0; k < 4; ++k) {
      int u = tid + 256 * k;              // u = 2*j + r
      ldsu[(u & 1) * 512 + (u >> 1)] = src[u];
    }
    __syncthreads();
    // software-pipelined B fragments: reads for t+2 issue before consuming t
    f16x8 b0 = lf[q * 512 + 0 * 32 + nn];
    f16x8 b1 = lf[q * 512 + 1 * 32 + nn];
    for (int t = 0; t < 16; t += 2) {
      int tn = (t + 2) & 15;               // wrap on last iter (harmless reread)
      f16x8 nb0 = lf[q * 512 + tn * 32 + nn];
      f16x8 nb1 = lf[q * 512 + (tn + 1) * 32 + nn];
      f32x16 d0 = __builtin_amdgcn_mfma_f32_32x32x16_f16(af0, b0, zc, 0, 0, 0);
      f32x16 d1 = __builtin_amdgcn_mfma_f32_32x32x16_f16(af0, b1, zc, 0, 0, 0);
#pragma unroll
      for (int i = 0; i < 16; ++i) m0[i] = fminf(fminf(d0[i], d1[i]), m0[i]);
      float c00 = min16(d0), c01 = min16(d1);
      f32x16 d2 = __builtin_amdgcn_mfma_f32_32x32x16_f16(af1, b0, zc, 0, 0, 0);
      f32x16 d3 = __builtin_amdgcn_mfma_f32_32x32x16_f16(af1, b1, zc, 0, 0, 0);
#pragma unroll
      for (int i = 0; i < 16; ++i) m1[i] = fminf(fminf(d2[i], d3[i]), m1[i]);
      // col-min over this wave's 64 rows: reg tree + q-half swap
      float c0 = fminf(c00, min16(d2));
      float c1 = fminf(c01, min16(d3));
      c0 = fminf(c0, __shfl_xor(c0, 32, 64));
      c1 = fminf(c1, __shfl_xor(c1, 32, 64));
      if (q == 0) {
        colmin_s[wave][t * 32 + nn] = c0;
        colmin_s[wave][(t + 1) * 32 + nn] = c1;
      }
      b0 = nb0; b1 = nb1;
    }
    __syncthreads();
    // cross-wave col-min combine -> global (overlaps next chunk's staging;
    // next chunk's colmin_s writes are fenced by the post-staging barrier)
    float* pc = pcol + ((size_t)b * 32 + wgrow) * NN + eighth * 1024 + chunk * 512;
#pragma unroll
    for (int e = 0; e < 2; ++e) {
      int c = tid + 256 * e;
      float v = fminf(fminf(colmin_s[0][c], colmin_s[1][c]),
                      fminf(colmin_s[2][c], colmin_s[3][c]));
      pc[c] = fmaxf(v, 0.0f);
    }
  }

  // row-min: reduce over col-lanes (xor within 32-lane halves), then store.
  // C/D layout: col=lane&31, row=(reg&3)+8*(reg>>2)+4*(lane>>5)
#pragma unroll
  for (int i = 0; i < 16; ++i) {
    float v = m0[i];
    v = fminf(v, __shfl_xor(v, 1, 64));
    v = fminf(v, __shfl_xor(v, 2, 64));
    v = fminf(v, __shfl_xor(v, 4, 64));
    v = fminf(v, __shfl_xor(v, 8, 64));
    v = fminf(v, __shfl_xor(v, 16, 64));
    m0[i] = fmaxf(v, 0.0f);
    v = m1[i];
    v = fminf(v, __shfl_xor(v, 1, 64));
    v = fminf(v, __shfl_xor(v, 2, 64));
    v = fminf(v, __shfl_xor(v, 4, 64));
    v = fminf(v, __shfl_xor(v, 8, 64));
    v = fminf(v, __shfl_xor(v, 16, 64));
    m1[i] = fmaxf(v, 0.0f);
  }
  float* pb = prow + ((size_t)b * 8 + eighth) * NN + wgrow * 256 + wave * 64;
#pragma unroll
  for (int reg = 0; reg < 16; ++reg) {
    int rit = (reg & 3) + 8 * (reg >> 2) + 4 * q;
    if (nn == reg) { pb[rit] = m0[reg]; pb[32 + rit] = m1[reg]; }
  }
}

// ---------------- K3: reduction into res[12] ----------------
// blocks 0..31: acc (b(4) x 8 row-segs of 1024; min over 8 eighth-planes)
// blocks 32..95: com (b(4) x 16 col-segs of 512; min over 32 wgrow rows, mask)
__global__ __launch_bounds__(256) void k_red(
    const float* __restrict__ prow, const float* __restrict__ pcol,
    const int* __restrict__ valid, float* __restrict__ res) {
  int bid = blockIdx.x, tid = threadIdx.x;
  __shared__ float r1[256], r2[256];
  float sum = 0.0f, cnt = 0.0f;
  if (bid < 32) {
    int bb = bid >> 3, seg = bid & 7;
#pragma unroll
    for (int k = 0; k < 4; ++k) {
      int r = seg * 1024 + tid + 256 * k;
      const float* p = prow + (size_t)bb * 8 * NN + r;
      float v = p[0];
#pragma unroll
      for (int e = 1; e < 8; ++e) v = fminf(v, p[(size_t)e * NN]);
      sum += v;
    }
    r1[tid] = sum;
    __syncthreads();
    for (int off = 128; off > 0; off >>= 1) {
      if (tid < off) r1[tid] += r1[tid + off];
      __syncthreads();
    }
    if (tid == 0) atomicAdd(&res[bb], r1[0]);
  } else {
    int g = bid - 32;
    int bb = g >> 4, seg = g & 15;
#pragma unroll
    for (int k = 0; k < 2; ++k) {
      int j = seg * 512 + tid + 256 * k;
      const float* p = pcol + (size_t)bb * 32 * NN + j;
      float v = p[0];
#pragma unroll
      for (int w = 1; w < 32; ++w) v = fminf(v, p[(size_t)w * NN]);
      int vld = valid[bb * NN + j] != 0;
      sum += vld ? v : 0.0f;
      cnt += vld ? 1.0f : 0.0f;
    }
    r1[tid] = sum; r2[tid] = cnt;
    __syncthreads();
    for (int off = 128; off > 0; off >>= 1) {
      if (tid < off) { r1[tid] += r1[tid + off]; r2[tid] += r2[tid + off]; }
      __syncthreads();
    }
    if (tid == 0) {
      atomicAdd(&res[4 + bb], r1[0]);
      atomicAdd(&res[8 + bb], r2[0]);
    }
  }
}

// ---------------- K4: final scalar ----------------
__global__ void k_final(const float* __restrict__ res, float* __restrict__ out) {
  if (threadIdx.x == 0 && blockIdx.x == 0) {
    float a = 0.f, c = 0.f;
    for (int bb = 0; bb < 4; ++bb) {
      a += res[bb] / (float)NN;
      c += res[4 + bb] / fmaxf(res[8 + bb], 1.0f);
    }
    out[0] = 0.5f * (a + c);   // 2*(a/4 + c/4)
  }
}

extern "C" void kernel_launch(void* const* d_in, const int* in_sizes, int n_in,
                              void* d_out, int out_size, void* d_ws, size_t ws_size,
                              hipStream_t stream) {
  const float* pr    = (const float*)d_in[0];
  const float* gt    = (const float*)d_in[1];
  const int*   valid = (const int*)d_in[2];

  f16* base = (f16*)d_ws;
  f16* APR = base;
  f16* BGT = base + SZ_PACK;
  float* prow = (float*)((char*)d_ws + OFF_PROW_BYTES);
  float* pcol = (float*)((char*)d_ws + OFF_PCOL_BYTES);
  float* res  = (float*)((char*)d_ws + OFF_RES_BYTES);

  k_init<<<(BB * NN) / 256, 256, 0, stream>>>(pr, gt, valid, APR, BGT, res);
  k_dist<<<1024, 256, 0, stream>>>(APR, BGT, prow, pcol);
  k_red<<<96, 256, 0, stream>>>(prow, pcol, valid, res);
  k_final<<<1, 64, 0, stream>>>(res, (float*)d_out);
}